// Round 5
// baseline (72.147 us; speedup 1.0000x reference)
//
#include <hip/hip_runtime.h>

typedef unsigned short u16;
typedef unsigned int   u32;
typedef float f32x4 __attribute__((ext_vector_type(4)));
typedef u16   u16x8 __attribute__((ext_vector_type(8)));
typedef short s16x8 __attribute__((ext_vector_type(8)));
typedef u32   u32x4 __attribute__((ext_vector_type(4)));

#define B_  8
#define S_  4096
#define D_  2048
#define E_  64
#define M_  (B_ * S_)
#define BM  64
#define BK  64
#define KSPLIT 2
#define KLEN (D_ / KSPLIT)
#define NT  (KLEN / BK)     // 16 k-tiles per block

__device__ __forceinline__ u16 f2bf(float f) {
  u32 u = __builtin_bit_cast(u32, f);
  u += 0x7fffu + ((u >> 16) & 1u);
  return (u16)(u >> 16);
}
__device__ __forceinline__ float bf2f(u16 h) {
  u32 u = ((u32)h) << 16;
  return __builtin_bit_cast(float, u);
}
__device__ __forceinline__ u32 cvtpk_bf16(float a, float b) {
  u32 r;
  asm("v_cvt_pk_bf16_f32 %0, %1, %2" : "=v"(r) : "v"(a), "v"(b));
  return r;
}

// split 8 consecutive f32 into hi/lo bf16 fragments (RNE hi, residual lo)
__device__ __forceinline__ void split8v(f32x4 f0, f32x4 f1, s16x8& hi, s16x8& lo) {
  u32x4 h, l;
  float fa[8] = {f0[0], f0[1], f0[2], f0[3], f1[0], f1[1], f1[2], f1[3]};
  #pragma unroll
  for (int j = 0; j < 4; ++j) {
    float a = fa[2 * j], b = fa[2 * j + 1];
    u32 hw = cvtpk_bf16(a, b);
    float ra = a - __builtin_bit_cast(float, hw << 16);
    float rb = b - __builtin_bit_cast(float, hw & 0xffff0000u);
    l[j] = cvtpk_bf16(ra, rb);
    h[j] = hw;
  }
  hi = __builtin_bit_cast(s16x8, h);
  lo = __builtin_bit_cast(s16x8, l);
}

__device__ __forceinline__ void gload16(const void* g, void* l) {
  __builtin_amdgcn_global_load_lds(
      (const __attribute__((address_space(1))) void*)g,
      (__attribute__((address_space(3))) void*)l, 16, 0, 0);
}
__device__ __forceinline__ f32x4 mfma16(s16x8 a, s16x8 b, f32x4 c) {
  return __builtin_amdgcn_mfma_f32_16x16x32_bf16(a, b, c, 0, 0, 0);
}

// ---------------- merged prep: blocks 0-7 compaction, blocks 8+ W conversion ----
__launch_bounds__(1024)
__global__ void prep_kernel(const float* __restrict__ W,
                            u16* __restrict__ whiT, u16* __restrict__ wloT,
                            const int* __restrict__ idxs,
                            int* __restrict__ compact, int* __restrict__ posmap,
                            int* __restrict__ count) {
  __shared__ u32 flag[S_];
  __shared__ int wtot[16], wpre[16];
  const int t = threadIdx.x;

  if (blockIdx.x >= 8) {
    // ---- W [D][E] fp32 -> hi/lo bf16 transposed [E][D] ----
    int i = (blockIdx.x - 8) * 1024 + t;   // 0 .. D*E-1
    int k = i >> 6;
    int e = i & 63;
    float w = W[i];
    u16 h = f2bf(w);
    u16 l = f2bf(w - bf2f(h));
    whiT[(size_t)e * D_ + k] = h;
    wloT[(size_t)e * D_ + k] = l;
    return;
  }

  // ---- per-batch unique-index compaction: flags + block scan ----
  const int b = blockIdx.x;
  const int lane = t & 63, wid = t >> 6;

  #pragma unroll
  for (int j = 0; j < 4; ++j) flag[t + j * 1024] = 0;
  __syncthreads();
  #pragma unroll
  for (int j = 0; j < 4; ++j) flag[idxs[b * S_ + t + j * 1024]] = 1;
  __syncthreads();

  int f[4], s = 0;
  #pragma unroll
  for (int j = 0; j < 4; ++j) { f[j] = (int)flag[t * 4 + j]; s += f[j]; }
  int inc = s;
  #pragma unroll
  for (int off = 1; off < 64; off <<= 1) {
    int v = __shfl_up(inc, off);
    if (lane >= off) inc += v;
  }
  if (lane == 63) wtot[wid] = inc;
  __syncthreads();
  if (t == 0) {
    int acc = 0;
    for (int w = 0; w < 16; ++w) { wpre[w] = acc; acc += wtot[w]; }
    count[b] = acc;
  }
  __syncthreads();
  int p = wpre[wid] + inc - s;   // exclusive prefix for this thread
  #pragma unroll
  for (int j = 0; j < 4; ++j) {
    int g = t * 4 + j;
    if (f[j]) {
      compact[b * S_ + p] = g;
      posmap[b * S_ + g] = p;
      ++p;
    }
  }
}

// ---------------- GEMM: compacted rows, 2-phase double-buffer, counted vmcnt ----
__launch_bounds__(256)
__global__ void router_gemm(const float* __restrict__ A,      // [8][4096][2048]
                            const u16* __restrict__ WhiT,     // [64][2048]
                            const u16* __restrict__ WloT,
                            const int* __restrict__ compact,  // [8][4096]
                            const int* __restrict__ count,    // [8]
                            float* __restrict__ Cp) {         // [KSPLIT][8][4096][64]
  __shared__ __align__(16) float Asm[2][BM * BK];   // 2 x 16 KB (XOR-swizzled)
  __shared__ __align__(16) u16 Whi[2][E_ * BK];     // 2 x 8 KB
  __shared__ __align__(16) u16 Wlo[2][E_ * BK];     // 2 x 8 KB

  const int b    = blockIdx.x >> 6;
  const int tile = blockIdx.x & 63;
  const int row0 = tile * BM;
  const int cnt  = count[b];
  if (row0 >= cnt) return;

  const int t    = threadIdx.x;
  const int lane = t & 63;
  const int wid  = t >> 6;
  const int fr   = lane & 15;
  const int fk   = lane >> 4;                // 0..3 (k-subgroup)
  const int kbeg = blockIdx.y * KLEN;

  // --- staging source pointers (pre-swizzled global addresses, rule #21) ---
  const float* asrc[4];
  #pragma unroll
  for (int g = 0; g < 4; ++g) {
    int row = g * 16 + (t >> 4);
    int cb  = ((t & 15) * 16) ^ ((row & 7) << 4);
    int rr  = row0 + row; if (rr >= cnt) rr = cnt - 1;
    int grow = compact[b * S_ + rr];
    asrc[g] = A + ((size_t)b * S_ + grow) * D_ + kbeg + (cb >> 2);
  }
  const u16* whsrc[2];
  const u16* wlsrc[2];
  #pragma unroll
  for (int g = 0; g < 2; ++g) {
    int e  = g * 32 + (t >> 3);
    int cb = ((t & 7) * 16) ^ ((e & 7) << 4);
    whsrc[g] = WhiT + (size_t)e * D_ + kbeg + (cb >> 1);
    wlsrc[g] = WloT + (size_t)e * D_ + kbeg + (cb >> 1);
  }

  // --- LDS read byte offsets (swizzled), static across k-iters ---
  const int arow = wid * 16 + fr;
  const int axr  = (arow & 7) << 4;
  u32 aoff[2][2];
  #pragma unroll
  for (int ks = 0; ks < 2; ++ks) {
    aoff[ks][0] = arow * 256 + ((ks * 128 + fk * 32) ^ axr);
    aoff[ks][1] = arow * 256 + ((ks * 128 + fk * 32 + 16) ^ axr);
  }
  u32 woff[2][4];
  #pragma unroll
  for (int n = 0; n < 4; ++n) {
    int e = n * 16 + fr;
    int xe = (e & 7) << 4;
    #pragma unroll
    for (int ks = 0; ks < 2; ++ks)
      woff[ks][n] = e * 128 + ((ks * 64 + fk * 16) ^ xe);
  }

  f32x4 acc[4] = {};

  // ---- staging macro: 8 gload_lds into buffer `buf` for k-tile offset `koff` ----
  #define STAGE(buf, koff)                                                         \
    do {                                                                           \
      _Pragma("unroll")                                                            \
      for (int g = 0; g < 4; ++g)                                                  \
        gload16(asrc[g] + (koff), (char*)Asm[buf] + (size_t)(g * 256 + t) * 16);   \
      _Pragma("unroll")                                                            \
      for (int g = 0; g < 2; ++g) {                                                \
        gload16(whsrc[g] + (koff), (char*)Whi[buf] + (size_t)(g * 128 + (t & 127)) * 16 + ((t >> 7) ? 0 : 0)); \
        gload16(wlsrc[g] + (koff), (char*)Wlo[buf] + (size_t)(g * 128 + t) * 16);  \
      }                                                                            \
    } while (0)

  // NOTE: W staging must cover 8KB with 512 x 16B slots across 256 threads x 2 issues:
  // slot index = g*256 + t  (same as round 4). The macro above had a typo risk; use
  // explicit code instead:
  #undef STAGE
  #define STAGE(buf, koff)                                                         \
    do {                                                                           \
      _Pragma("unroll")                                                            \
      for (int g = 0; g < 4; ++g)                                                  \
        gload16(asrc[g] + (koff), (char*)Asm[buf] + (size_t)(g * 256 + t) * 16);   \
      _Pragma("unroll")                                                            \
      for (int g = 0; g < 2; ++g) {                                                \
        gload16(whsrc[g] + (koff), (char*)Whi[buf] + (size_t)(g * 256 + t) * 16);  \
        gload16(wlsrc[g] + (koff), (char*)Wlo[buf] + (size_t)(g * 256 + t) * 16);  \
      }                                                                            \
    } while (0)

  #define COMPUTE(buf)                                                             \
    do {                                                                           \
      const char* aL = (const char*)Asm[buf];                                      \
      const char* hL = (const char*)Whi[buf];                                      \
      const char* lL = (const char*)Wlo[buf];                                      \
      _Pragma("unroll")                                                            \
      for (int ks = 0; ks < 2; ++ks) {                                             \
        f32x4 af0 = *(const f32x4*)(aL + aoff[ks][0]);                             \
        f32x4 af1 = *(const f32x4*)(aL + aoff[ks][1]);                             \
        s16x8 ah, al;                                                              \
        split8v(af0, af1, ah, al);                                                 \
        _Pragma("unroll")                                                          \
        for (int n = 0; n < 4; ++n) {                                              \
          s16x8 wh = *(const s16x8*)(hL + woff[ks][n]);                            \
          s16x8 wl = *(const s16x8*)(lL + woff[ks][n]);                            \
          acc[n] = mfma16(al, wh, acc[n]);                                         \
          acc[n] = mfma16(ah, wl, acc[n]);                                         \
          acc[n] = mfma16(ah, wh, acc[n]);                                         \
        }                                                                          \
      }                                                                            \
    } while (0)

  // ---- prologue: fill buf0 ----
  STAGE(0, 0);

  // ---- main loop: compute tile tt from buf[tt&1], prefetch tt+1 into buf[~] ----
  for (int tt = 0; tt < NT - 1; ++tt) {
    const int cur = tt & 1;
    STAGE(cur ^ 1, (tt + 1) * BK);                  // prefetch next tile (stays in flight)
    asm volatile("s_waitcnt vmcnt(8)" ::: "memory"); // wait ONLY prior tile's 8 loads
    __builtin_amdgcn_s_barrier();                    // all waves: buf[cur] fully landed
    __builtin_amdgcn_sched_barrier(0);
    COMPUTE(cur);
    __builtin_amdgcn_s_barrier();                    // reads done before buf[cur] reuse
    __builtin_amdgcn_sched_barrier(0);
  }
  // ---- peeled last tile: nothing in flight behind it ----
  asm volatile("s_waitcnt vmcnt(0)" ::: "memory");
  __builtin_amdgcn_s_barrier();
  __builtin_amdgcn_sched_barrier(0);
  COMPUTE((NT - 1) & 1);

  // epilogue: C/D layout col = lane&15, row = (lane>>4)*4 + reg
  float* cb = Cp + ((size_t)blockIdx.y * B_ + b) * S_ * E_;
  const int orow = row0 + wid * 16 + (lane >> 4) * 4;
  #pragma unroll
  for (int n = 0; n < 4; ++n) {
    int ocol = n * 16 + fr;
    #pragma unroll
    for (int r = 0; r < 4; ++r)
      cb[(size_t)(orow + r) * E_ + ocol] = acc[n][r];
  }
  #undef STAGE
  #undef COMPUTE
}

// ---------------- top-4 + softmax + scatter ----------------
__launch_bounds__(256)
__global__ void topk_kernel(const float* __restrict__ Cp,     // [KSPLIT][8][4096][64]
                            const int* __restrict__ idxs,     // [8][4096]
                            const int* __restrict__ posmap,   // [8][4096]
                            float* __restrict__ out) {        // [8][4096][64]
  const int lane = threadIdx.x & 63;
  const int wid  = threadIdx.x >> 6;
  const int r    = blockIdx.x * 4 + wid;
  const int b    = r >> 12;
  const int idx  = idxs[r];
  const int p    = posmap[(size_t)b * S_ + idx];

  size_t off = ((size_t)b * S_ + p) * E_ + lane;
  float cur = Cp[off] + Cp[(size_t)B_ * S_ * E_ + off];

  float vals[4];
  int   inds[4];
  #pragma unroll
  for (int tk = 0; tk < 4; ++tk) {
    float mv = cur;
    int   mi = lane;
    #pragma unroll
    for (int off2 = 32; off2 > 0; off2 >>= 1) {
      float ov = __shfl_xor(mv, off2);
      int   oi = __shfl_xor(mi, off2);
      if (ov > mv || (ov == mv && oi < mi)) { mv = ov; mi = oi; }  // tie -> smaller index
    }
    vals[tk] = mv;
    inds[tk] = mi;
    if (lane == mi) cur = -INFINITY;
  }

  float w[4], ssum = 0.f;
  #pragma unroll
  for (int tk = 0; tk < 4; ++tk) { w[tk] = __expf(vals[tk] - vals[0]); ssum += w[tk]; }
  float inv = 1.f / ssum;
  float o = 0.f;
  #pragma unroll
  for (int tk = 0; tk < 4; ++tk)
    if (lane == inds[tk]) o = w[tk] * inv;

  out[(size_t)r * E_ + lane] = o;
}

// ---------------- host ----------------
extern "C" void kernel_launch(void* const* d_in, const int* in_sizes, int n_in,
                              void* d_out, int out_size, void* d_ws, size_t ws_size,
                              hipStream_t stream) {
  const float* hidden = (const float*)d_in[0];
  const int*   idxs   = (const int*)d_in[1];
  const float* W      = (const float*)d_in[2];
  float* out = (float*)d_out;

  // ws: Cp [2][8][4096][64] f32 (16MB) | WhiT (256KB) | WloT (256KB)
  //     | compact (128KB) | posmap (128KB) | count (32B)
  char* wsp = (char*)d_ws;
  float* Cp = (float*)wsp;                       wsp += (size_t)KSPLIT * M_ * E_ * 4;
  u16* whiT = (u16*)wsp;                         wsp += (size_t)E_ * D_ * 2;
  u16* wloT = (u16*)wsp;                         wsp += (size_t)E_ * D_ * 2;
  int* compact = (int*)wsp;                      wsp += (size_t)M_ * 4;
  int* posmap  = (int*)wsp;                      wsp += (size_t)M_ * 4;
  int* count   = (int*)wsp;

  prep_kernel<<<8 + (D_ * E_) / 1024, 1024, 0, stream>>>(W, whiT, wloT, idxs,
                                                          compact, posmap, count);
  dim3 g(B_ * 64, KSPLIT);
  router_gemm<<<g, 256, 0, stream>>>(hidden, whiT, wloT, compact, count, Cp);
  topk_kernel<<<M_ / 4, 256, 0, stream>>>(Cp, idxs, posmap, out);
}

// Round 6
// 65.732 us; speedup vs baseline: 1.0976x; 1.0976x over previous
//
#include <hip/hip_runtime.h>

typedef unsigned short u16;
typedef unsigned int   u32;
typedef float f32x4 __attribute__((ext_vector_type(4)));
typedef u16   u16x8 __attribute__((ext_vector_type(8)));
typedef short s16x8 __attribute__((ext_vector_type(8)));
typedef u32   u32x4 __attribute__((ext_vector_type(4)));

#define B_  8
#define S_  4096
#define D_  2048
#define E_  64
#define M_  (B_ * S_)
#define BM  64
#define BK  64
#define KSPLIT 4
#define KLEN (D_ / KSPLIT)   // 512
#define NT  (KLEN / BK)      // 8 k-tiles per block

__device__ __forceinline__ u16 f2bf(float f) {
  u32 u = __builtin_bit_cast(u32, f);
  u += 0x7fffu + ((u >> 16) & 1u);
  return (u16)(u >> 16);
}
__device__ __forceinline__ float bf2f(u16 h) {
  u32 u = ((u32)h) << 16;
  return __builtin_bit_cast(float, u);
}
__device__ __forceinline__ u32 cvtpk_bf16(float a, float b) {
  u32 r;
  asm("v_cvt_pk_bf16_f32 %0, %1, %2" : "=v"(r) : "v"(a), "v"(b));
  return r;
}

// split 8 consecutive f32 into hi/lo bf16 fragments (RNE hi, residual lo)
__device__ __forceinline__ void split8v(f32x4 f0, f32x4 f1, s16x8& hi, s16x8& lo) {
  u32x4 h, l;
  float fa[8] = {f0[0], f0[1], f0[2], f0[3], f1[0], f1[1], f1[2], f1[3]};
  #pragma unroll
  for (int j = 0; j < 4; ++j) {
    float a = fa[2 * j], b = fa[2 * j + 1];
    u32 hw = cvtpk_bf16(a, b);
    float ra = a - __builtin_bit_cast(float, hw << 16);
    float rb = b - __builtin_bit_cast(float, hw & 0xffff0000u);
    l[j] = cvtpk_bf16(ra, rb);
    h[j] = hw;
  }
  hi = __builtin_bit_cast(s16x8, h);
  lo = __builtin_bit_cast(s16x8, l);
}

__device__ __forceinline__ void gload16(const void* g, void* l) {
  __builtin_amdgcn_global_load_lds(
      (const __attribute__((address_space(1))) void*)g,
      (__attribute__((address_space(3))) void*)l, 16, 0, 0);
}
__device__ __forceinline__ f32x4 mfma16(s16x8 a, s16x8 b, f32x4 c) {
  return __builtin_amdgcn_mfma_f32_16x16x32_bf16(a, b, c, 0, 0, 0);
}

// ---------------- merged prep: blocks 0-7 compaction, blocks 8+ W conversion ----
__launch_bounds__(1024)
__global__ void prep_kernel(const float* __restrict__ W,
                            u16* __restrict__ whiT, u16* __restrict__ wloT,
                            const int* __restrict__ idxs,
                            int* __restrict__ compact, int* __restrict__ posmap,
                            int* __restrict__ count) {
  __shared__ u32 flag[S_];
  __shared__ int wtot[16], wpre[16];
  const int t = threadIdx.x;

  if (blockIdx.x >= 8) {
    // ---- W [D][E] fp32 -> hi/lo bf16 transposed [E][D] ----
    int i = (blockIdx.x - 8) * 1024 + t;   // 0 .. D*E-1
    int k = i >> 6;
    int e = i & 63;
    float w = W[i];
    u16 h = f2bf(w);
    u16 l = f2bf(w - bf2f(h));
    whiT[(size_t)e * D_ + k] = h;
    wloT[(size_t)e * D_ + k] = l;
    return;
  }

  // ---- per-batch unique-index compaction: flags + block scan ----
  const int b = blockIdx.x;
  const int lane = t & 63, wid = t >> 6;

  #pragma unroll
  for (int j = 0; j < 4; ++j) flag[t + j * 1024] = 0;
  __syncthreads();
  #pragma unroll
  for (int j = 0; j < 4; ++j) flag[idxs[b * S_ + t + j * 1024]] = 1;
  __syncthreads();

  int f[4], s = 0;
  #pragma unroll
  for (int j = 0; j < 4; ++j) { f[j] = (int)flag[t * 4 + j]; s += f[j]; }
  int inc = s;
  #pragma unroll
  for (int off = 1; off < 64; off <<= 1) {
    int v = __shfl_up(inc, off);
    if (lane >= off) inc += v;
  }
  if (lane == 63) wtot[wid] = inc;
  __syncthreads();
  if (t == 0) {
    int acc = 0;
    for (int w = 0; w < 16; ++w) { wpre[w] = acc; acc += wtot[w]; }
    count[b] = acc;
  }
  __syncthreads();
  int p = wpre[wid] + inc - s;   // exclusive prefix for this thread
  #pragma unroll
  for (int j = 0; j < 4; ++j) {
    int g = t * 4 + j;
    if (f[j]) {
      compact[b * S_ + p] = g;
      posmap[b * S_ + g] = p;
      ++p;
    }
  }
}

// ---------------- GEMM: compacted rows, single-buffer, KSPLIT=4 for occupancy ----
__launch_bounds__(256, 4)
__global__ void router_gemm(const float* __restrict__ A,      // [8][4096][2048]
                            const u16* __restrict__ WhiT,     // [64][2048]
                            const u16* __restrict__ WloT,
                            const int* __restrict__ compact,  // [8][4096]
                            const int* __restrict__ count,    // [8]
                            float* __restrict__ Cp) {         // [KSPLIT][8][4096][64]
  __shared__ __align__(16) float Asm[BM * BK];     // 16 KB, XOR-swizzled layout
  __shared__ __align__(16) u16 Whi[E_ * BK];       // 8 KB
  __shared__ __align__(16) u16 Wlo[E_ * BK];       // 8 KB

  const int b    = blockIdx.x >> 6;
  const int tile = blockIdx.x & 63;
  const int row0 = tile * BM;
  const int cnt  = count[b];
  if (row0 >= cnt) return;

  const int t    = threadIdx.x;
  const int lane = t & 63;
  const int wid  = t >> 6;
  const int fr   = lane & 15;
  const int fk   = lane >> 4;                // 0..3 (k-subgroup)
  const int kbeg = blockIdx.y * KLEN;

  // --- staging source pointers (pre-swizzled global addresses, rule #21) ---
  // A: issue g covers physical LDS bytes (g*256+t)*16; row = g*16 + (t>>4);
  //    logical col byte = ((t&15)*16) ^ ((row&7)<<4)
  const float* asrc[4];
  #pragma unroll
  for (int g = 0; g < 4; ++g) {
    int row = g * 16 + (t >> 4);
    int cb  = ((t & 15) * 16) ^ ((row & 7) << 4);
    int rr  = row0 + row; if (rr >= cnt) rr = cnt - 1;
    int grow = compact[b * S_ + rr];
    asrc[g] = A + ((size_t)b * S_ + grow) * D_ + kbeg + (cb >> 2);
  }
  // W: issue g covers bytes (g*256+t)*16; e = g*32 + (t>>3);
  //    logical col byte = ((t&7)*16) ^ ((e&7)<<4)
  const u16* whsrc[2];
  const u16* wlsrc[2];
  #pragma unroll
  for (int g = 0; g < 2; ++g) {
    int e  = g * 32 + (t >> 3);
    int cb = ((t & 7) * 16) ^ ((e & 7) << 4);
    whsrc[g] = WhiT + (size_t)e * D_ + kbeg + (cb >> 1);
    wlsrc[g] = WloT + (size_t)e * D_ + kbeg + (cb >> 1);
  }

  // --- LDS read byte offsets (swizzled), static across k-iters ---
  const int arow = wid * 16 + fr;
  const int axr  = (arow & 7) << 4;
  u32 aoff[2][2];
  #pragma unroll
  for (int ks = 0; ks < 2; ++ks) {
    aoff[ks][0] = arow * 256 + ((ks * 128 + fk * 32) ^ axr);
    aoff[ks][1] = arow * 256 + ((ks * 128 + fk * 32 + 16) ^ axr);
  }
  u32 woff[2][4];
  #pragma unroll
  for (int n = 0; n < 4; ++n) {
    int e = n * 16 + fr;
    int xe = (e & 7) << 4;
    #pragma unroll
    for (int ks = 0; ks < 2; ++ks)
      woff[ks][n] = e * 128 + ((ks * 64 + fk * 16) ^ xe);
  }

  f32x4 acc[4] = {};
  const char* aL = (const char*)Asm;
  const char* hL = (const char*)Whi;
  const char* lL = (const char*)Wlo;

  for (int koff = 0; koff < KLEN; koff += BK) {
    // stage tile (single buffer: previous compute finished at loop-tail barrier)
    #pragma unroll
    for (int g = 0; g < 4; ++g)
      gload16(asrc[g] + koff, (char*)Asm + (size_t)(g * 256 + t) * 16);
    #pragma unroll
    for (int g = 0; g < 2; ++g) {
      gload16(whsrc[g] + koff, (char*)Whi + (size_t)(g * 256 + t) * 16);
      gload16(wlsrc[g] + koff, (char*)Wlo + (size_t)(g * 256 + t) * 16);
    }
    __syncthreads();   // compiler drains vmcnt(0) before s_barrier

    #pragma unroll
    for (int ks = 0; ks < 2; ++ks) {
      f32x4 af0 = *(const f32x4*)(aL + aoff[ks][0]);
      f32x4 af1 = *(const f32x4*)(aL + aoff[ks][1]);
      s16x8 ah, al;
      split8v(af0, af1, ah, al);
      #pragma unroll
      for (int n = 0; n < 4; ++n) {
        s16x8 wh = *(const s16x8*)(hL + woff[ks][n]);
        s16x8 wl = *(const s16x8*)(lL + woff[ks][n]);
        acc[n] = mfma16(al, wh, acc[n]);
        acc[n] = mfma16(ah, wl, acc[n]);
        acc[n] = mfma16(ah, wh, acc[n]);
      }
    }
    __syncthreads();
  }

  // epilogue: C/D layout col = lane&15, row = (lane>>4)*4 + reg
  float* cb = Cp + ((size_t)blockIdx.y * B_ + b) * S_ * E_;
  const int orow = row0 + wid * 16 + (lane >> 4) * 4;
  #pragma unroll
  for (int n = 0; n < 4; ++n) {
    int ocol = n * 16 + fr;
    #pragma unroll
    for (int r = 0; r < 4; ++r)
      cb[(size_t)(orow + r) * E_ + ocol] = acc[n][r];
  }
}

// ---------------- top-4 + softmax + scatter ----------------
__launch_bounds__(256)
__global__ void topk_kernel(const float* __restrict__ Cp,     // [KSPLIT][8][4096][64]
                            const int* __restrict__ idxs,     // [8][4096]
                            const int* __restrict__ posmap,   // [8][4096]
                            float* __restrict__ out) {        // [8][4096][64]
  const int lane = threadIdx.x & 63;
  const int wid  = threadIdx.x >> 6;
  const int r    = blockIdx.x * 4 + wid;
  const int b    = r >> 12;
  const int idx  = idxs[r];
  const int p    = posmap[(size_t)b * S_ + idx];

  size_t off = ((size_t)b * S_ + p) * E_ + lane;
  float cur = 0.f;
  #pragma unroll
  for (int ps = 0; ps < KSPLIT; ++ps)
    cur += Cp[(size_t)ps * M_ * E_ + off];

  float vals[4];
  int   inds[4];
  #pragma unroll
  for (int tk = 0; tk < 4; ++tk) {
    float mv = cur;
    int   mi = lane;
    #pragma unroll
    for (int off2 = 32; off2 > 0; off2 >>= 1) {
      float ov = __shfl_xor(mv, off2);
      int   oi = __shfl_xor(mi, off2);
      if (ov > mv || (ov == mv && oi < mi)) { mv = ov; mi = oi; }  // tie -> smaller index
    }
    vals[tk] = mv;
    inds[tk] = mi;
    if (lane == mi) cur = -INFINITY;
  }

  float w[4], ssum = 0.f;
  #pragma unroll
  for (int tk = 0; tk < 4; ++tk) { w[tk] = __expf(vals[tk] - vals[0]); ssum += w[tk]; }
  float inv = 1.f / ssum;
  float o = 0.f;
  #pragma unroll
  for (int tk = 0; tk < 4; ++tk)
    if (lane == inds[tk]) o = w[tk] * inv;

  out[(size_t)r * E_ + lane] = o;
}

// ---------------- host ----------------
extern "C" void kernel_launch(void* const* d_in, const int* in_sizes, int n_in,
                              void* d_out, int out_size, void* d_ws, size_t ws_size,
                              hipStream_t stream) {
  const float* hidden = (const float*)d_in[0];
  const int*   idxs   = (const int*)d_in[1];
  const float* W      = (const float*)d_in[2];
  float* out = (float*)d_out;

  // ws: Cp [4][8][4096][64] f32 (32MB) | WhiT (256KB) | WloT (256KB)
  //     | compact (128KB) | posmap (128KB) | count (32B)
  char* wsp = (char*)d_ws;
  float* Cp = (float*)wsp;                       wsp += (size_t)KSPLIT * M_ * E_ * 4;
  u16* whiT = (u16*)wsp;                         wsp += (size_t)E_ * D_ * 2;
  u16* wloT = (u16*)wsp;                         wsp += (size_t)E_ * D_ * 2;
  int* compact = (int*)wsp;                      wsp += (size_t)M_ * 4;
  int* posmap  = (int*)wsp;                      wsp += (size_t)M_ * 4;
  int* count   = (int*)wsp;

  prep_kernel<<<8 + (D_ * E_) / 1024, 1024, 0, stream>>>(W, whiT, wloT, idxs,
                                                          compact, posmap, count);
  dim3 g(B_ * 64, KSPLIT);
  router_gemm<<<g, 256, 0, stream>>>(hidden, whiT, wloT, compact, count, Cp);
  topk_kernel<<<M_ / 4, 256, 0, stream>>>(Cp, idxs, posmap, out);
}